// Round 2
// baseline (6601.752 us; speedup 1.0000x reference)
//
#include <hip/hip_runtime.h>

typedef _Float16 half8 __attribute__((ext_vector_type(8)));
typedef _Float16 half4 __attribute__((ext_vector_type(4)));
typedef float    f32x4 __attribute__((ext_vector_type(4)));

#define N_NODES 65536
#define N_EDGES 131072
#define BB      2048
#define HDIM    300
#define HPAD    320   // K padded to multiple of 32
#define ECHUNK  32768
#define NCHUNK  4

// ---------------- prepack: dst[384][Kpad] = W[k][n]  (B^T panel, zero-padded)
__global__ __launch_bounds__(256) void prepack_w(const float* __restrict__ src,
                                                 _Float16* __restrict__ dst,
                                                 int Kpad, int Kreal) {
    int idx = blockIdx.x * 256 + threadIdx.x;
    int n = idx / Kpad, k = idx - n * Kpad;
    if (n >= 384) return;
    float v = (n < 300 && k < Kreal) ? src[k * 300 + n] : 0.f;
    dst[idx] = (_Float16)v;
}

__global__ __launch_bounds__(256) void cvt_x(const float* __restrict__ x,
                                             _Float16* __restrict__ xh, int n) {
    int i = blockIdx.x * 256 + threadIdx.x;
    if (i < n) xh[i] = (_Float16)x[i];
}

// e [E,16] f32 -> e16 [E,32] f16 zero-padded
__global__ __launch_bounds__(256) void cvt_e(const float* __restrict__ e,
                                             _Float16* __restrict__ e16) {
    int i = blockIdx.x * 256 + threadIdx.x;
    if (i >= N_EDGES * 32) return;
    int k = i & 31, row = i >> 5;
    e16[i] = (_Float16)(k < 16 ? e[row * 16 + k] : 0.f);
}

// ---------------- MFMA GEMM: out[M][320] = op( A[M][K] (+A2) @ Bp^T ) + bias
// Bp is [384][K] f16: row n holds W[:,n].  128x128 tile, 4 waves, 64x64/wave.
template <bool FUSE, bool RELU>
__global__ __launch_bounds__(256) void gemm_f16(
        const _Float16* __restrict__ A, const float* __restrict__ A2,
        const _Float16* __restrict__ Bp, const float* __restrict__ bias,
        _Float16* __restrict__ out, int M, int K) {
    __shared__ _Float16 As[128 * 40];   // row stride 40 (80B) breaks bank conflicts
    __shared__ _Float16 Bs[128 * 40];

    int bx = blockIdx.x;
    int nt = bx % 3, mt = bx / 3;
    int m0 = mt * 128, n0 = nt * 128;
    int t = threadIdx.x;
    int lane = t & 63, w = t >> 6;
    int wr = w >> 1, wc = w & 1;

    f32x4 acc[4][4] = {};

    for (int k0 = 0; k0 < K; k0 += 32) {
        __syncthreads();
        // stage A and B: 2 chunks of 8 halves per thread each
        #pragma unroll
        for (int cc = 0; cc < 2; ++cc) {
            int c = t + cc * 256;
            int row = c >> 2, ko = (c & 3) << 3;
            half8 av = *(const half8*)&A[(size_t)(m0 + row) * K + k0 + ko];
            if (FUSE) {
                const float* ap = &A2[(size_t)(m0 + row) * K + k0 + ko];
                f32x4 g0 = *(const f32x4*)ap, g1 = *(const f32x4*)(ap + 4);
                #pragma unroll
                for (int j = 0; j < 4; ++j) av[j]     = (_Float16)((float)av[j]     + g0[j]);
                #pragma unroll
                for (int j = 0; j < 4; ++j) av[j + 4] = (_Float16)((float)av[j + 4] + g1[j]);
            }
            *(half8*)&As[row * 40 + ko] = av;
            half8 bv = *(const half8*)&Bp[(size_t)(n0 + row) * K + k0 + ko];
            *(half8*)&Bs[row * 40 + ko] = bv;
        }
        __syncthreads();

        int lr = lane & 15, lk = (lane >> 4) << 3;
        half8 af[4], bf[4];
        #pragma unroll
        for (int i = 0; i < 4; ++i)
            af[i] = *(const half8*)&As[(wr * 64 + i * 16 + lr) * 40 + lk];
        #pragma unroll
        for (int j = 0; j < 4; ++j)
            bf[j] = *(const half8*)&Bs[(wc * 64 + j * 16 + lr) * 40 + lk];
        #pragma unroll
        for (int i = 0; i < 4; ++i)
            #pragma unroll
            for (int j = 0; j < 4; ++j)
                acc[i][j] = __builtin_amdgcn_mfma_f32_16x16x32_f16(af[i], bf[j], acc[i][j], 0, 0, 0);
    }

    // epilogue: D mapping col=lane&15, row=(lane>>4)*4+q
    int lr = lane & 15, lq = (lane >> 4) * 4;
    #pragma unroll
    for (int j = 0; j < 4; ++j) {
        int col = n0 + wc * 64 + j * 16 + lr;
        if (col >= 300) continue;
        float bv = bias[col];
        #pragma unroll
        for (int i = 0; i < 4; ++i) {
            int rbase = m0 + wr * 64 + i * 16 + lq;
            #pragma unroll
            for (int q = 0; q < 4; ++q) {
                float v = acc[i][j][q] + bv;
                if (RELU) v = v > 0.f ? v : 0.f;
                out[(size_t)(rbase + q) * HPAD + col] = (_Float16)v;
            }
        }
    }
}

// ---------------- message + scatter: agg[dst] += relu(h[src] + ehc)  (edge chunk)
__global__ __launch_bounds__(256) void message_scatter(
        const _Float16* __restrict__ h, const _Float16* __restrict__ ehc,
        const int* __restrict__ src, const int* __restrict__ dst, int e0,
        float* __restrict__ agg) {
    int idx = blockIdx.x * 256 + threadIdx.x;       // ECHUNK * 75 chunks of 4 cols
    if (idx >= ECHUNK * 75) return;
    int el = idx / 75, c = idx - el * 75;
    int s = src[e0 + el], d = dst[e0 + el];
    half4 hv = *(const half4*)&h[(size_t)s * HPAD + c * 4];
    half4 ev = *(const half4*)&ehc[(size_t)el * HPAD + c * 4];
    #pragma unroll
    for (int j = 0; j < 4; ++j) {
        float m = (float)hv[j] + (float)ev[j];
        if (m > 0.f) atomicAdd(&agg[(size_t)d * HPAD + c * 4 + j], m);
    }
}

// ---------------- per-molecule sum pool (32 consecutive rows)
__global__ __launch_bounds__(128) void pool_kernel(const _Float16* __restrict__ h,
                                                   float* __restrict__ out, int add) {
    int b = blockIdx.x, t = threadIdx.x;
    if (t >= 75) return;
    float a0 = 0, a1 = 0, a2 = 0, a3 = 0;
    for (int r = 0; r < 32; ++r) {
        half4 v = *(const half4*)&h[(size_t)(b * 32 + r) * HPAD + t * 4];
        a0 += (float)v[0]; a1 += (float)v[1]; a2 += (float)v[2]; a3 += (float)v[3];
    }
    f32x4 o = {a0, a1, a2, a3};
    if (add) o += *(f32x4*)&out[b * 300 + t * 4];
    *(f32x4*)&out[b * 300 + t * 4] = o;
}

__global__ __launch_bounds__(256) void diff_kernel(float* __restrict__ reaction,
                                                   const float* __restrict__ reactants,
                                                   const float* __restrict__ products, int n) {
    int i = blockIdx.x * 256 + threadIdx.x;
    if (i < n) reaction[i] = reactants[i] - products[i];
}

extern "C" void kernel_launch(void* const* d_in, const int* in_sizes, int n_in,
                              void* d_out, int out_size, void* d_ws, size_t ws_size,
                              hipStream_t stream) {
    const float* x[3]   = {(const float*)d_in[0], (const float*)d_in[5],  (const float*)d_in[10]};
    const float* ein[3] = {(const float*)d_in[1], (const float*)d_in[6],  (const float*)d_in[11]};
    const int*   src[3] = {(const int*)d_in[2],   (const int*)d_in[7],    (const int*)d_in[12]};
    const int*   dst[3] = {(const int*)d_in[3],   (const int*)d_in[8],    (const int*)d_in[13]};
    const float* Wn = (const float*)d_in[15];
    const float* bn = (const float*)d_in[16];
    const float* We = (const float*)d_in[17];
    const float* be = (const float*)d_in[18];
    const float* W1 = (const float*)d_in[19];
    const float* b1 = (const float*)d_in[20];
    const float* W2 = (const float*)d_in[21];
    const float* b2 = (const float*)d_in[22];

    char* ws = (char*)d_ws;
    size_t off = 0;
    auto alloc = [&](size_t bytes) {
        char* p = ws + off; off += (bytes + 1023) & ~(size_t)1023; return p;
    };
    _Float16* h    = (_Float16*)alloc((size_t)N_NODES * HPAD * 2);   // 40 MiB
    _Float16* tbuf = (_Float16*)alloc((size_t)N_NODES * HPAD * 2);   // 40 MiB
    float*    agg  = (float*)   alloc((size_t)N_NODES * HPAD * 4);   // 80 MiB
    _Float16* e16  = (_Float16*)alloc((size_t)N_EDGES * 32 * 2);     //  8 MiB
    _Float16* ehc  = (_Float16*)alloc((size_t)ECHUNK * HPAD * 2);    // 20 MiB
    _Float16* Wt1  = (_Float16*)alloc((size_t)3 * 384 * HPAD * 2);
    _Float16* Wt2  = (_Float16*)alloc((size_t)3 * 384 * HPAD * 2);
    _Float16* Wnt  = (_Float16*)alloc((size_t)384 * 64 * 2);
    _Float16* Wet  = (_Float16*)alloc((size_t)384 * 32 * 2);
    // xh overlays agg: dead before first agg memset
    _Float16* xh   = (_Float16*)agg;                                 // needs 8 MiB < 80 MiB

    if (off > ws_size) return;   // graceful diagnostic failure (absmax ~61.75) if ws too small

    for (int l = 0; l < 3; ++l) {
        prepack_w<<<(384 * HPAD + 255) / 256, 256, 0, stream>>>(W1 + l * 90000, Wt1 + l * 384 * HPAD, HPAD, 300);
        prepack_w<<<(384 * HPAD + 255) / 256, 256, 0, stream>>>(W2 + l * 90000, Wt2 + l * 384 * HPAD, HPAD, 300);
    }
    prepack_w<<<(384 * 64 + 255) / 256, 256, 0, stream>>>(Wn, Wnt, 64, 64);
    prepack_w<<<(384 * 32 + 255) / 256, 256, 0, stream>>>(We, Wet, 32, 16);

    // zero h/t once so K-pad columns (300..319) stay 0 for all GEMM reads
    hipMemsetAsync(h,    0, (size_t)N_NODES * HPAD * 2, stream);
    hipMemsetAsync(tbuf, 0, (size_t)N_NODES * HPAD * 2, stream);

    float* outp      = (float*)d_out;
    float* reaction  = outp;
    float* reactants = outp + (size_t)BB * HDIM;
    float* products  = outp + (size_t)2 * BB * HDIM;

    for (int g = 0; g < 3; ++g) {
        cvt_x<<<(N_NODES * 64 + 255) / 256, 256, 0, stream>>>(x[g], xh, N_NODES * 64);
        // h = relu(x @ Wn + bn)
        gemm_f16<false, true ><<<512 * 3, 256, 0, stream>>>(xh, nullptr, Wnt, bn, h, N_NODES, 64);
        cvt_e<<<(N_EDGES * 32 + 255) / 256, 256, 0, stream>>>(ein[g], e16);
        for (int l = 0; l < 3; ++l) {
            hipMemsetAsync(agg, 0, (size_t)N_NODES * HPAD * 4, stream);
            for (int c = 0; c < NCHUNK; ++c) {
                // ehc = e_chunk @ We + be   (recomputed per layer to save workspace)
                gemm_f16<false, false><<<(ECHUNK / 128) * 3, 256, 0, stream>>>(
                    e16 + (size_t)c * ECHUNK * 32, nullptr, Wet, be, ehc, ECHUNK, 32);
                message_scatter<<<(ECHUNK * 75 + 255) / 256, 256, 0, stream>>>(
                    h, ehc, src[g], dst[g], c * ECHUNK, agg);
            }
            // t = relu((h+agg) @ W1[l] + b1[l])
            gemm_f16<true, true><<<512 * 3, 256, 0, stream>>>(h, agg, Wt1 + l * 384 * HPAD, b1 + l * 300, tbuf, N_NODES, HPAD);
            // h = t @ W2[l] + b2[l]  (+relu if l<2)
            if (l < 2)
                gemm_f16<false, true ><<<512 * 3, 256, 0, stream>>>(tbuf, nullptr, Wt2 + l * 384 * HPAD, b2 + l * 300, h, N_NODES, HPAD);
            else
                gemm_f16<false, false><<<512 * 3, 256, 0, stream>>>(tbuf, nullptr, Wt2 + l * 384 * HPAD, b2 + l * 300, h, N_NODES, HPAD);
        }
        if (g == 0)      pool_kernel<<<BB, 128, 0, stream>>>(h, reactants, 0);
        else if (g == 1) pool_kernel<<<BB, 128, 0, stream>>>(h, reactants, 1);
        else             pool_kernel<<<BB, 128, 0, stream>>>(h, products, 0);
    }
    diff_kernel<<<((BB * HDIM) + 255) / 256, 256, 0, stream>>>(reaction, reactants, products, BB * HDIM);
}

// Round 3
// 1763.285 us; speedup vs baseline: 3.7440x; 3.7440x over previous
//
#include <hip/hip_runtime.h>

typedef _Float16 half8 __attribute__((ext_vector_type(8)));
typedef _Float16 half4 __attribute__((ext_vector_type(4)));
typedef float    f32x4 __attribute__((ext_vector_type(4)));

#define N_NODES 65536
#define N_EDGES 131072
#define BB      2048
#define HDIM    300
#define HPAD    320   // K padded to multiple of 32

// ---------------- prepack: dst[384][Kpad] = W[k][n]  (B^T panel, zero-padded)
__global__ __launch_bounds__(256) void prepack_w(const float* __restrict__ src,
                                                 _Float16* __restrict__ dst,
                                                 int Kpad, int Kreal) {
    int idx = blockIdx.x * 256 + threadIdx.x;
    int n = idx / Kpad, k = idx - n * Kpad;
    if (n >= 384) return;
    float v = (n < 300 && k < Kreal) ? src[k * 300 + n] : 0.f;
    dst[idx] = (_Float16)v;
}

__global__ __launch_bounds__(256) void cvt_x(const float* __restrict__ x,
                                             _Float16* __restrict__ xh, int n) {
    int i = blockIdx.x * 256 + threadIdx.x;
    if (i < n) xh[i] = (_Float16)x[i];
}

// ---------------- MFMA GEMM: out[M][320] = op( A[M][K] @ Bp^T ) + bias
// Bp is [384][K] f16: row n holds W[:,n].  128x128 tile, 4 waves, 64x64/wave.
// Pad cols 300..319 are written as exact zeros (so no init memsets needed).
template <bool RELU>
__global__ __launch_bounds__(256) void gemm_f16(
        const _Float16* __restrict__ A,
        const _Float16* __restrict__ Bp, const float* __restrict__ bias,
        _Float16* __restrict__ out, int M, int K) {
    __shared__ _Float16 As[128 * 40];   // row stride 40 (80B) breaks bank conflicts
    __shared__ _Float16 Bs[128 * 40];

    int bx = blockIdx.x;
    int nt = bx % 3, mt = bx / 3;
    int m0 = mt * 128, n0 = nt * 128;
    int t = threadIdx.x;
    int lane = t & 63, w = t >> 6;
    int wr = w >> 1, wc = w & 1;

    f32x4 acc[4][4] = {};

    for (int k0 = 0; k0 < K; k0 += 32) {
        __syncthreads();
        #pragma unroll
        for (int cc = 0; cc < 2; ++cc) {
            int c = t + cc * 256;
            int row = c >> 2, ko = (c & 3) << 3;
            half8 av = *(const half8*)&A[(size_t)(m0 + row) * K + k0 + ko];
            *(half8*)&As[row * 40 + ko] = av;
            half8 bv = *(const half8*)&Bp[(size_t)(n0 + row) * K + k0 + ko];
            *(half8*)&Bs[row * 40 + ko] = bv;
        }
        __syncthreads();

        int lr = lane & 15, lk = (lane >> 4) << 3;
        half8 af[4], bf[4];
        #pragma unroll
        for (int i = 0; i < 4; ++i)
            af[i] = *(const half8*)&As[(wr * 64 + i * 16 + lr) * 40 + lk];
        #pragma unroll
        for (int j = 0; j < 4; ++j)
            bf[j] = *(const half8*)&Bs[(wc * 64 + j * 16 + lr) * 40 + lk];
        #pragma unroll
        for (int i = 0; i < 4; ++i)
            #pragma unroll
            for (int j = 0; j < 4; ++j)
                acc[i][j] = __builtin_amdgcn_mfma_f32_16x16x32_f16(af[i], bf[j], acc[i][j], 0, 0, 0);
    }

    // epilogue: D mapping col=lane&15, row=(lane>>4)*4+q
    int lr = lane & 15, lq = (lane >> 4) * 4;
    #pragma unroll
    for (int j = 0; j < 4; ++j) {
        int col = n0 + wc * 64 + j * 16 + lr;
        if (col >= HPAD) continue;
        float bv = (col < 300) ? bias[col] : 0.f;
        #pragma unroll
        for (int i = 0; i < 4; ++i) {
            int rbase = m0 + wr * 64 + i * 16 + lq;
            #pragma unroll
            for (int q = 0; q < 4; ++q) {
                float v = acc[i][j][q] + bv;
                if (RELU) v = v > 0.f ? v : 0.f;
                if (col >= 300) v = 0.f;
                out[(size_t)(rbase + q) * HPAD + col] = (_Float16)v;
            }
        }
    }
}

// ---------------- CSR build ----------------
__global__ __launch_bounds__(256) void hist_kernel(const int* __restrict__ dst,
                                                   int* __restrict__ counts) {
    int e = blockIdx.x * 256 + threadIdx.x;
    if (e < N_EDGES) atomicAdd(&counts[dst[e]], 1);
}

// exclusive scan of 256 elements per block; emits block sums
__global__ __launch_bounds__(256) void scan_block(const int* __restrict__ in,
                                                  int* __restrict__ partial,
                                                  int* __restrict__ bsum, int nb) {
    __shared__ int s[256];
    int b = blockIdx.x, t = threadIdx.x;
    int v = (b < nb) ? in[b * 256 + t] : 0;
    s[t] = v;
    __syncthreads();
    for (int o = 1; o < 256; o <<= 1) {
        int x = (t >= o) ? s[t - o] : 0;
        __syncthreads();
        s[t] += x;
        __syncthreads();
    }
    partial[b * 256 + t] = s[t] - v;      // exclusive
    if (t == 255 && bsum) bsum[b] = s[255];
}

__global__ __launch_bounds__(256) void add_offsets(const int* __restrict__ partial,
                                                   const int* __restrict__ boff,
                                                   int* __restrict__ rowptr) {
    int i = blockIdx.x * 256 + threadIdx.x;
    if (i < N_NODES) rowptr[i] = partial[i] + boff[i >> 8];
    if (i == 0) rowptr[N_NODES] = N_EDGES;
}

__global__ __launch_bounds__(256) void scatter_csr(const int* __restrict__ src,
                                                   const int* __restrict__ dst,
                                                   const int* __restrict__ rowptr,
                                                   int* __restrict__ cnt,
                                                   int2* __restrict__ se) {
    int e = blockIdx.x * 256 + threadIdx.x;
    if (e >= N_EDGES) return;
    int d = dst[e];
    int pos = atomicAdd(&cnt[d], 1);
    se[rowptr[d] + pos] = make_int2(src[e], e);
}

// ---------------- gather: z[d] = h[d] + sum_{e: dst=d} relu(h[src_e] + (e_e@We + be))
// 320 thr/block = 4 node-slots x 80 col-chunks (chunks 75..79 write pad zeros).
// Each thread keeps its 4-col We strip (16 x f32x4) in registers.
__global__ __launch_bounds__(320) void gather_z(
        const _Float16* __restrict__ h, const float* __restrict__ ein,
        const float* __restrict__ We, const float* __restrict__ be,
        const int2* __restrict__ se, const int* __restrict__ rowptr,
        _Float16* __restrict__ z, int nblocks) {
    int t = threadIdx.x;
    int c = t % 80, ns = t / 80;
    bool active = c < 75;
    f32x4 w[16];
    f32x4 bias4 = {0.f, 0.f, 0.f, 0.f};
    if (active) {
        #pragma unroll
        for (int k = 0; k < 16; ++k)
            w[k] = *(const f32x4*)&We[k * 300 + c * 4];
        bias4 = *(const f32x4*)&be[c * 4];
    }
    for (int node = blockIdx.x * 4 + ns; node < N_NODES; node += nblocks * 4) {
        f32x4 sum = {0.f, 0.f, 0.f, 0.f};
        if (active) {
            half4 hn = *(const half4*)&h[(size_t)node * HPAD + c * 4];
            #pragma unroll
            for (int j = 0; j < 4; ++j) sum[j] = (float)hn[j];
            int r0 = rowptr[node], r1 = rowptr[node + 1];
            for (int s = r0; s < r1; ++s) {
                int2 p = se[s];
                half4 hv = *(const half4*)&h[(size_t)p.x * HPAD + c * 4];
                const float* ep = &ein[(size_t)p.y * 16];
                f32x4 e0 = *(const f32x4*)ep;
                f32x4 e1 = *(const f32x4*)(ep + 4);
                f32x4 e2 = *(const f32x4*)(ep + 8);
                f32x4 e3 = *(const f32x4*)(ep + 12);
                f32x4 eh = bias4;
                #pragma unroll
                for (int k = 0; k < 4; ++k) eh += e0[k] * w[k];
                #pragma unroll
                for (int k = 0; k < 4; ++k) eh += e1[k] * w[4 + k];
                #pragma unroll
                for (int k = 0; k < 4; ++k) eh += e2[k] * w[8 + k];
                #pragma unroll
                for (int k = 0; k < 4; ++k) eh += e3[k] * w[12 + k];
                #pragma unroll
                for (int j = 0; j < 4; ++j) {
                    float m = (float)hv[j] + eh[j];
                    sum[j] += m > 0.f ? m : 0.f;
                }
            }
        }
        half4 o;
        #pragma unroll
        for (int j = 0; j < 4; ++j) o[j] = (_Float16)sum[j];
        *(half4*)&z[(size_t)node * HPAD + c * 4] = o;
    }
}

// ---------------- per-molecule sum pool (32 consecutive rows)
__global__ __launch_bounds__(128) void pool_kernel(const _Float16* __restrict__ h,
                                                   float* __restrict__ out, int add) {
    int b = blockIdx.x, t = threadIdx.x;
    if (t >= 75) return;
    float a0 = 0, a1 = 0, a2 = 0, a3 = 0;
    for (int r = 0; r < 32; ++r) {
        half4 v = *(const half4*)&h[(size_t)(b * 32 + r) * HPAD + t * 4];
        a0 += (float)v[0]; a1 += (float)v[1]; a2 += (float)v[2]; a3 += (float)v[3];
    }
    f32x4 o = {a0, a1, a2, a3};
    if (add) o += *(f32x4*)&out[b * 300 + t * 4];
    *(f32x4*)&out[b * 300 + t * 4] = o;
}

__global__ __launch_bounds__(256) void diff_kernel(float* __restrict__ reaction,
                                                   const float* __restrict__ reactants,
                                                   const float* __restrict__ products, int n) {
    int i = blockIdx.x * 256 + threadIdx.x;
    if (i < n) reaction[i] = reactants[i] - products[i];
}

extern "C" void kernel_launch(void* const* d_in, const int* in_sizes, int n_in,
                              void* d_out, int out_size, void* d_ws, size_t ws_size,
                              hipStream_t stream) {
    const float* x[3]   = {(const float*)d_in[0], (const float*)d_in[5],  (const float*)d_in[10]};
    const float* ein[3] = {(const float*)d_in[1], (const float*)d_in[6],  (const float*)d_in[11]};
    const int*   src[3] = {(const int*)d_in[2],   (const int*)d_in[7],    (const int*)d_in[12]};
    const int*   dst[3] = {(const int*)d_in[3],   (const int*)d_in[8],    (const int*)d_in[13]};
    const float* Wn = (const float*)d_in[15];
    const float* bn = (const float*)d_in[16];
    const float* We = (const float*)d_in[17];
    const float* be = (const float*)d_in[18];
    const float* W1 = (const float*)d_in[19];
    const float* b1 = (const float*)d_in[20];
    const float* W2 = (const float*)d_in[21];
    const float* b2 = (const float*)d_in[22];

    char* ws = (char*)d_ws;
    size_t off = 0;
    auto alloc = [&](size_t bytes) {
        char* p = ws + off; off += (bytes + 1023) & ~(size_t)1023; return p;
    };
    _Float16* h     = (_Float16*)alloc((size_t)N_NODES * HPAD * 2);   // 40 MiB
    _Float16* zbuf  = (_Float16*)alloc((size_t)N_NODES * HPAD * 2);   // 40 MiB
    _Float16* tbuf  = (_Float16*)alloc((size_t)N_NODES * HPAD * 2);   // 40 MiB
    int*      counts= (int*)alloc((size_t)N_NODES * 4);
    int*      part  = (int*)alloc((size_t)N_NODES * 4);
    int*      bsum  = (int*)alloc(256 * 4);
    int*      bpart = (int*)alloc(256 * 4);
    int*      bzero = (int*)alloc(4);
    int*      rowptr= (int*)alloc((size_t)(N_NODES + 1) * 4);
    int*      cnt   = (int*)alloc((size_t)N_NODES * 4);
    int2*     se    = (int2*)alloc((size_t)N_EDGES * 8);
    _Float16* Wt1   = (_Float16*)alloc((size_t)3 * 384 * HPAD * 2);
    _Float16* Wt2   = (_Float16*)alloc((size_t)3 * 384 * HPAD * 2);
    _Float16* Wnt   = (_Float16*)alloc((size_t)384 * 64 * 2);
    _Float16* xh    = (_Float16*)zbuf;   // overlay: dead before gather writes zbuf

    if (off > ws_size) return;   // graceful diagnostic failure if ws too small

    for (int l = 0; l < 3; ++l) {
        prepack_w<<<(384 * HPAD + 255) / 256, 256, 0, stream>>>(W1 + l * 90000, Wt1 + l * 384 * HPAD, HPAD, 300);
        prepack_w<<<(384 * HPAD + 255) / 256, 256, 0, stream>>>(W2 + l * 90000, Wt2 + l * 384 * HPAD, HPAD, 300);
    }
    prepack_w<<<(384 * 64 + 255) / 256, 256, 0, stream>>>(Wn, Wnt, 64, 64);
    hipMemsetAsync(bzero, 0, 4, stream);

    float* outp      = (float*)d_out;
    float* reaction  = outp;
    float* reactants = outp + (size_t)BB * HDIM;
    float* products  = outp + (size_t)2 * BB * HDIM;

    const int EG = (N_EDGES + 255) / 256;
    for (int g = 0; g < 3; ++g) {
        // node projection: h = relu(x @ Wn + bn)
        cvt_x<<<(N_NODES * 64 + 255) / 256, 256, 0, stream>>>(x[g], xh, N_NODES * 64);
        gemm_f16<true><<<512 * 3, 256, 0, stream>>>(xh, Wnt, bn, h, N_NODES, 64);

        // CSR build (incoming edges per node)
        hipMemsetAsync(counts, 0, (size_t)N_NODES * 4, stream);
        hist_kernel<<<EG, 256, 0, stream>>>(dst[g], counts);
        scan_block<<<256, 256, 0, stream>>>(counts, part, bsum, 256);
        scan_block<<<1, 256, 0, stream>>>(bsum, bpart, bzero, 1);
        add_offsets<<<256, 256, 0, stream>>>(part, bpart, rowptr);
        hipMemsetAsync(cnt, 0, (size_t)N_NODES * 4, stream);
        scatter_csr<<<EG, 256, 0, stream>>>(src[g], dst[g], rowptr, cnt, se);

        for (int l = 0; l < 3; ++l) {
            gather_z<<<2048, 320, 0, stream>>>(h, ein[g], We, be, se, rowptr, zbuf, 2048);
            // t = relu(z @ W1[l] + b1[l])
            gemm_f16<true><<<512 * 3, 256, 0, stream>>>(zbuf, Wt1 + l * 384 * HPAD, b1 + l * 300, tbuf, N_NODES, HPAD);
            // h = t @ W2[l] + b2[l]  (+relu if l<2)
            if (l < 2)
                gemm_f16<true ><<<512 * 3, 256, 0, stream>>>(tbuf, Wt2 + l * 384 * HPAD, b2 + l * 300, h, N_NODES, HPAD);
            else
                gemm_f16<false><<<512 * 3, 256, 0, stream>>>(tbuf, Wt2 + l * 384 * HPAD, b2 + l * 300, h, N_NODES, HPAD);
        }
        if (g == 0)      pool_kernel<<<BB, 128, 0, stream>>>(h, reactants, 0);
        else if (g == 1) pool_kernel<<<BB, 128, 0, stream>>>(h, reactants, 1);
        else             pool_kernel<<<BB, 128, 0, stream>>>(h, products, 0);
    }
    diff_kernel<<<((BB * HDIM) + 255) / 256, 256, 0, stream>>>(reaction, reactants, products, BB * HDIM);
}

// Round 4
// 1533.139 us; speedup vs baseline: 4.3060x; 1.1501x over previous
//
#include <hip/hip_runtime.h>

typedef _Float16 half8 __attribute__((ext_vector_type(8)));
typedef _Float16 half4 __attribute__((ext_vector_type(4)));
typedef float    f32x4 __attribute__((ext_vector_type(4)));

#define N_NODES 65536
#define N_EDGES 131072
#define BB      2048
#define HDIM    300
#define HPAD    320   // K padded to multiple of 32

// ---------------- prepack: dst[384][Kpad] = W[k][n]  (B^T panel, zero-padded)
__global__ __launch_bounds__(256) void prepack_w(const float* __restrict__ src,
                                                 _Float16* __restrict__ dst,
                                                 int Kpad, int Kreal) {
    int idx = blockIdx.x * 256 + threadIdx.x;
    int n = idx / Kpad, k = idx - n * Kpad;
    if (n >= 384) return;
    float v = (n < 300 && k < Kreal) ? src[k * 300 + n] : 0.f;
    dst[idx] = (_Float16)v;
}

__global__ __launch_bounds__(256) void cvt_x(const float* __restrict__ x,
                                             _Float16* __restrict__ xh, int n) {
    int i = blockIdx.x * 256 + threadIdx.x;
    if (i < n) xh[i] = (_Float16)x[i];
}

// ---------------- MFMA GEMM: out[M][320] = op( A[M][K] @ Bp^T ) + bias
// Bp is [384][K] f16: row n holds W[:,n].  128x128 tile, 4 waves, 64x64/wave.
// Pad cols 300..319 are written as exact zeros (so no init memsets needed).
template <bool RELU>
__global__ __launch_bounds__(256) void gemm_f16(
        const _Float16* __restrict__ A,
        const _Float16* __restrict__ Bp, const float* __restrict__ bias,
        _Float16* __restrict__ out, int M, int K) {
    __shared__ _Float16 As[128 * 40];   // row stride 40 (80B) breaks bank conflicts
    __shared__ _Float16 Bs[128 * 40];

    int bx = blockIdx.x;
    int nt = bx % 3, mt = bx / 3;
    int m0 = mt * 128, n0 = nt * 128;
    int t = threadIdx.x;
    int lane = t & 63, w = t >> 6;
    int wr = w >> 1, wc = w & 1;

    f32x4 acc[4][4] = {};

    for (int k0 = 0; k0 < K; k0 += 32) {
        __syncthreads();
        #pragma unroll
        for (int cc = 0; cc < 2; ++cc) {
            int c = t + cc * 256;
            int row = c >> 2, ko = (c & 3) << 3;
            half8 av = *(const half8*)&A[(size_t)(m0 + row) * K + k0 + ko];
            *(half8*)&As[row * 40 + ko] = av;
            half8 bv = *(const half8*)&Bp[(size_t)(n0 + row) * K + k0 + ko];
            *(half8*)&Bs[row * 40 + ko] = bv;
        }
        __syncthreads();

        int lr = lane & 15, lk = (lane >> 4) << 3;
        half8 af[4], bf[4];
        #pragma unroll
        for (int i = 0; i < 4; ++i)
            af[i] = *(const half8*)&As[(wr * 64 + i * 16 + lr) * 40 + lk];
        #pragma unroll
        for (int j = 0; j < 4; ++j)
            bf[j] = *(const half8*)&Bs[(wc * 64 + j * 16 + lr) * 40 + lk];
        #pragma unroll
        for (int i = 0; i < 4; ++i)
            #pragma unroll
            for (int j = 0; j < 4; ++j)
                acc[i][j] = __builtin_amdgcn_mfma_f32_16x16x32_f16(af[i], bf[j], acc[i][j], 0, 0, 0);
    }

    // epilogue: D mapping col=lane&15, row=(lane>>4)*4+q
    int lr = lane & 15, lq = (lane >> 4) * 4;
    #pragma unroll
    for (int j = 0; j < 4; ++j) {
        int col = n0 + wc * 64 + j * 16 + lr;
        if (col >= HPAD) continue;
        float bv = (col < 300) ? bias[col] : 0.f;
        #pragma unroll
        for (int i = 0; i < 4; ++i) {
            int rbase = m0 + wr * 64 + i * 16 + lq;
            #pragma unroll
            for (int q = 0; q < 4; ++q) {
                float v = acc[i][j][q] + bv;
                if (RELU) v = v > 0.f ? v : 0.f;
                if (col >= 300) v = 0.f;
                out[(size_t)(rbase + q) * HPAD + col] = (_Float16)v;
            }
        }
    }
}

// ---------------- CSR build ----------------
__global__ __launch_bounds__(256) void hist_kernel(const int* __restrict__ dst,
                                                   int* __restrict__ counts) {
    int e = blockIdx.x * 256 + threadIdx.x;
    if (e < N_EDGES) atomicAdd(&counts[dst[e]], 1);
}

// exclusive scan of 256 elements per block; emits block sums
__global__ __launch_bounds__(256) void scan_block(const int* __restrict__ in,
                                                  int* __restrict__ partial,
                                                  int* __restrict__ bsum, int nb) {
    __shared__ int s[256];
    int b = blockIdx.x, t = threadIdx.x;
    int v = (b < nb) ? in[b * 256 + t] : 0;
    s[t] = v;
    __syncthreads();
    for (int o = 1; o < 256; o <<= 1) {
        int x = (t >= o) ? s[t - o] : 0;
        __syncthreads();
        s[t] += x;
        __syncthreads();
    }
    partial[b * 256 + t] = s[t] - v;      // exclusive
    if (t == 255 && bsum) bsum[b] = s[255];
}

__global__ __launch_bounds__(256) void add_offsets(const int* __restrict__ partial,
                                                   const int* __restrict__ boff,
                                                   int* __restrict__ rowptr) {
    int i = blockIdx.x * 256 + threadIdx.x;
    if (i < N_NODES) rowptr[i] = partial[i] + boff[i >> 8];
    if (i == 0) rowptr[N_NODES] = N_EDGES;
}

__global__ __launch_bounds__(256) void scatter_csr(const int* __restrict__ src,
                                                   const int* __restrict__ dst,
                                                   const int* __restrict__ rowptr,
                                                   int* __restrict__ cnt,
                                                   int2* __restrict__ se) {
    int e = blockIdx.x * 256 + threadIdx.x;
    if (e >= N_EDGES) return;
    int d = dst[e];
    int pos = atomicAdd(&cnt[d], 1);
    se[rowptr[d] + pos] = make_int2(src[e], e);
}

// ---------------- gather: z[d] = h[d] + sum_{e: dst=d} relu(h[src_e] + (e_e@We + be))
// 320 thr/block = 4 node-slots x 80 col-chunks (chunks 75..79 write pad zeros).
// f16 math throughout (v_pk_fma_f16); batch-4 edges for memory-level parallelism.
__global__ __launch_bounds__(320) void gather_z(
        const _Float16* __restrict__ h, const _Float16* __restrict__ e16,
        const _Float16* __restrict__ wet, const _Float16* __restrict__ bet,
        const int2* __restrict__ se, const int* __restrict__ rowptr,
        _Float16* __restrict__ z, int nblocks) {
    int t = threadIdx.x;
    int c = t % 80, ns = t / 80;
    bool active = c < 75;
    half4 w[16];
    half4 bias4 = {(_Float16)0, (_Float16)0, (_Float16)0, (_Float16)0};
    if (active) {
        #pragma unroll
        for (int k = 0; k < 16; ++k)
            w[k] = *(const half4*)&wet[k * 300 + c * 4];
        bias4 = *(const half4*)&bet[c * 4];
    }
    for (int node = blockIdx.x * 4 + ns; node < N_NODES; node += nblocks * 4) {
        int r0 = rowptr[node], r1 = rowptr[node + 1];
        half4 acc = {(_Float16)0, (_Float16)0, (_Float16)0, (_Float16)0};
        half4 hn = acc;
        if (active) hn = *(const half4*)&h[(size_t)node * HPAD + c * 4];
        if (active) {
            for (int s = r0; s < r1; s += 4) {
                int nb = r1 - s;
                int i1 = s + (1 < nb ? 1 : 0);
                int i2 = s + (2 < nb ? 2 : 0);
                int i3 = s + (3 < nb ? 3 : 0);
                int2 p[4];
                p[0] = se[s]; p[1] = se[i1]; p[2] = se[i2]; p[3] = se[i3];
                half4 hv[4];
                #pragma unroll
                for (int u = 0; u < 4; ++u)
                    hv[u] = *(const half4*)&h[(size_t)p[u].x * HPAD + c * 4];
                #pragma unroll
                for (int u = 0; u < 4; ++u) {
                    const _Float16* ep = &e16[(size_t)p[u].y * 16];
                    half4 e0 = *(const half4*)ep;
                    half4 e1 = *(const half4*)(ep + 4);
                    half4 e2 = *(const half4*)(ep + 8);
                    half4 e3 = *(const half4*)(ep + 12);
                    half4 eh = bias4;
                    #pragma unroll
                    for (int k = 0; k < 4; ++k) eh += e0[k] * w[k];
                    #pragma unroll
                    for (int k = 0; k < 4; ++k) eh += e1[k] * w[4 + k];
                    #pragma unroll
                    for (int k = 0; k < 4; ++k) eh += e2[k] * w[8 + k];
                    #pragma unroll
                    for (int k = 0; k < 4; ++k) eh += e3[k] * w[12 + k];
                    half4 m = hv[u] + eh;
                    #pragma unroll
                    for (int j = 0; j < 4; ++j)
                        m[j] = m[j] > (_Float16)0 ? m[j] : (_Float16)0;
                    if (u < nb) acc += m;
                }
            }
        }
        half4 o = hn + acc;          // inactive lanes: 0 (pad cols 300..319)
        *(half4*)&z[(size_t)node * HPAD + c * 4] = o;
    }
}

// ---------------- per-molecule sum pool (32 consecutive rows)
__global__ __launch_bounds__(128) void pool_kernel(const _Float16* __restrict__ h,
                                                   float* __restrict__ out, int add) {
    int b = blockIdx.x, t = threadIdx.x;
    if (t >= 75) return;
    float a0 = 0, a1 = 0, a2 = 0, a3 = 0;
    for (int r = 0; r < 32; ++r) {
        half4 v = *(const half4*)&h[(size_t)(b * 32 + r) * HPAD + t * 4];
        a0 += (float)v[0]; a1 += (float)v[1]; a2 += (float)v[2]; a3 += (float)v[3];
    }
    f32x4 o = {a0, a1, a2, a3};
    if (add) o += *(f32x4*)&out[b * 300 + t * 4];
    *(f32x4*)&out[b * 300 + t * 4] = o;
}

__global__ __launch_bounds__(256) void diff_kernel(float* __restrict__ reaction,
                                                   const float* __restrict__ reactants,
                                                   const float* __restrict__ products, int n) {
    int i = blockIdx.x * 256 + threadIdx.x;
    if (i < n) reaction[i] = reactants[i] - products[i];
}

extern "C" void kernel_launch(void* const* d_in, const int* in_sizes, int n_in,
                              void* d_out, int out_size, void* d_ws, size_t ws_size,
                              hipStream_t stream) {
    const float* x[3]   = {(const float*)d_in[0], (const float*)d_in[5],  (const float*)d_in[10]};
    const float* ein[3] = {(const float*)d_in[1], (const float*)d_in[6],  (const float*)d_in[11]};
    const int*   src[3] = {(const int*)d_in[2],   (const int*)d_in[7],    (const int*)d_in[12]};
    const int*   dst[3] = {(const int*)d_in[3],   (const int*)d_in[8],    (const int*)d_in[13]};
    const float* Wn = (const float*)d_in[15];
    const float* bn = (const float*)d_in[16];
    const float* We = (const float*)d_in[17];
    const float* be = (const float*)d_in[18];
    const float* W1 = (const float*)d_in[19];
    const float* b1 = (const float*)d_in[20];
    const float* W2 = (const float*)d_in[21];
    const float* b2 = (const float*)d_in[22];

    char* ws = (char*)d_ws;
    size_t off = 0;
    auto alloc = [&](size_t bytes) {
        char* p = ws + off; off += (bytes + 1023) & ~(size_t)1023; return p;
    };
    _Float16* h     = (_Float16*)alloc((size_t)N_NODES * HPAD * 2);   // 40 MiB
    _Float16* zbuf  = (_Float16*)alloc((size_t)N_NODES * HPAD * 2);   // 40 MiB
    _Float16* tbuf  = (_Float16*)alloc((size_t)N_NODES * HPAD * 2);   // 40 MiB
    _Float16* e16   = (_Float16*)alloc((size_t)N_EDGES * 16 * 2);     //  4 MiB
    int*      counts= (int*)alloc((size_t)N_NODES * 4);
    int*      part  = (int*)alloc((size_t)N_NODES * 4);
    int*      bsum  = (int*)alloc(256 * 4);
    int*      bpart = (int*)alloc(256 * 4);
    int*      bzero = (int*)alloc(4);
    int*      rowptr= (int*)alloc((size_t)(N_NODES + 1) * 4);
    int*      cnt   = (int*)alloc((size_t)N_NODES * 4);
    int2*     se    = (int2*)alloc((size_t)N_EDGES * 8);
    _Float16* Wt1   = (_Float16*)alloc((size_t)3 * 384 * HPAD * 2);
    _Float16* Wt2   = (_Float16*)alloc((size_t)3 * 384 * HPAD * 2);
    _Float16* Wnt   = (_Float16*)alloc((size_t)384 * 64 * 2);
    _Float16* wet   = (_Float16*)alloc((size_t)16 * 300 * 2);
    _Float16* bet   = (_Float16*)alloc((size_t)300 * 2);
    _Float16* xh    = (_Float16*)zbuf;   // overlay: dead before gather writes zbuf

    if (off > ws_size) return;   // graceful diagnostic failure if ws too small

    for (int l = 0; l < 3; ++l) {
        prepack_w<<<(384 * HPAD + 255) / 256, 256, 0, stream>>>(W1 + l * 90000, Wt1 + l * 384 * HPAD, HPAD, 300);
        prepack_w<<<(384 * HPAD + 255) / 256, 256, 0, stream>>>(W2 + l * 90000, Wt2 + l * 384 * HPAD, HPAD, 300);
    }
    prepack_w<<<(384 * 64 + 255) / 256, 256, 0, stream>>>(Wn, Wnt, 64, 64);
    cvt_x<<<(16 * 300 + 255) / 256, 256, 0, stream>>>(We, wet, 16 * 300);
    cvt_x<<<(300 + 255) / 256, 256, 0, stream>>>(be, bet, 300);
    hipMemsetAsync(bzero, 0, 4, stream);

    float* outp      = (float*)d_out;
    float* reaction  = outp;
    float* reactants = outp + (size_t)BB * HDIM;
    float* products  = outp + (size_t)2 * BB * HDIM;

    const int EG = (N_EDGES + 255) / 256;
    for (int g = 0; g < 3; ++g) {
        // node projection: h = relu(x @ Wn + bn)
        cvt_x<<<(N_NODES * 64 + 255) / 256, 256, 0, stream>>>(x[g], xh, N_NODES * 64);
        gemm_f16<true><<<512 * 3, 256, 0, stream>>>(xh, Wnt, bn, h, N_NODES, 64);
        // edge features to f16 once per graph
        cvt_x<<<(N_EDGES * 16 + 255) / 256, 256, 0, stream>>>(ein[g], e16, N_EDGES * 16);

        // CSR build (incoming edges per node)
        hipMemsetAsync(counts, 0, (size_t)N_NODES * 4, stream);
        hist_kernel<<<EG, 256, 0, stream>>>(dst[g], counts);
        scan_block<<<256, 256, 0, stream>>>(counts, part, bsum, 256);
        scan_block<<<1, 256, 0, stream>>>(bsum, bpart, bzero, 1);
        add_offsets<<<256, 256, 0, stream>>>(part, bpart, rowptr);
        hipMemsetAsync(cnt, 0, (size_t)N_NODES * 4, stream);
        scatter_csr<<<EG, 256, 0, stream>>>(src[g], dst[g], rowptr, cnt, se);

        for (int l = 0; l < 3; ++l) {
            gather_z<<<2048, 320, 0, stream>>>(h, e16, wet, bet, se, rowptr, zbuf, 2048);
            // t = relu(z @ W1[l] + b1[l])
            gemm_f16<true><<<512 * 3, 256, 0, stream>>>(zbuf, Wt1 + l * 384 * HPAD, b1 + l * 300, tbuf, N_NODES, HPAD);
            // h = t @ W2[l] + b2[l]  (+relu if l<2)
            if (l < 2)
                gemm_f16<true ><<<512 * 3, 256, 0, stream>>>(tbuf, Wt2 + l * 384 * HPAD, b2 + l * 300, h, N_NODES, HPAD);
            else
                gemm_f16<false><<<512 * 3, 256, 0, stream>>>(tbuf, Wt2 + l * 384 * HPAD, b2 + l * 300, h, N_NODES, HPAD);
        }
        if (g == 0)      pool_kernel<<<BB, 128, 0, stream>>>(h, reactants, 0);
        else if (g == 1) pool_kernel<<<BB, 128, 0, stream>>>(h, reactants, 1);
        else             pool_kernel<<<BB, 128, 0, stream>>>(h, products, 0);
    }
    diff_kernel<<<((BB * HDIM) + 255) / 256, 256, 0, stream>>>(reaction, reactants, products, BB * HDIM);
}

// Round 5
// 1326.401 us; speedup vs baseline: 4.9772x; 1.1559x over previous
//
#include <hip/hip_runtime.h>

typedef _Float16 half8 __attribute__((ext_vector_type(8)));
typedef _Float16 half4 __attribute__((ext_vector_type(4)));
typedef float    f32x4 __attribute__((ext_vector_type(4)));

#define N_NODES 65536
#define N_EDGES 131072
#define BB      2048
#define HDIM    300
#define HPAD    320   // K padded to multiple of 32

// ---------------- prepack: dst[384][Kpad] = W[k][n]  (B^T panel, zero-padded)
__global__ __launch_bounds__(256) void prepack_w(const float* __restrict__ src,
                                                 _Float16* __restrict__ dst,
                                                 int Kpad, int Kreal) {
    int idx = blockIdx.x * 256 + threadIdx.x;
    int n = idx / Kpad, k = idx - n * Kpad;
    if (n >= 384) return;
    float v = (n < 300 && k < Kreal) ? src[k * 300 + n] : 0.f;
    dst[idx] = (_Float16)v;
}

__global__ __launch_bounds__(256) void cvt_x(const float* __restrict__ x,
                                             _Float16* __restrict__ xh, int n) {
    int i = blockIdx.x * 256 + threadIdx.x;
    if (i < n) xh[i] = (_Float16)x[i];
}

// edge feats -> f16, permuted into CSR order, zero-padded to 32 cols
__global__ __launch_bounds__(256) void cvt_e_csr(const float* __restrict__ ein,
                                                 const int2* __restrict__ se,
                                                 _Float16* __restrict__ ecsr) {
    int i = blockIdx.x * 256 + threadIdx.x;
    if (i >= N_EDGES * 32) return;
    int k = i & 31, s = i >> 5;
    int e = se[s].y;
    ecsr[i] = (_Float16)(k < 16 ? ein[(size_t)e * 16 + k] : 0.f);
}

// ---------------- MFMA GEMM: out[M][320] = op( A[M][K] @ Bp^T ) + bias
// Bp is [384][K] f16: row n holds W[:,n].  128x128 tile, 4 waves, 64x64/wave.
// Pad cols 300..319 are written as exact zeros.
template <bool RELU>
__global__ __launch_bounds__(256) void gemm_f16(
        const _Float16* __restrict__ A,
        const _Float16* __restrict__ Bp, const float* __restrict__ bias,
        _Float16* __restrict__ out, int M, int K) {
    __shared__ _Float16 As[128 * 40];   // row stride 40 (80B) breaks bank conflicts
    __shared__ _Float16 Bs[128 * 40];

    int bx = blockIdx.x;
    int nt = bx % 3, mt = bx / 3;
    int m0 = mt * 128, n0 = nt * 128;
    int t = threadIdx.x;
    int lane = t & 63, w = t >> 6;
    int wr = w >> 1, wc = w & 1;

    f32x4 acc[4][4] = {};

    for (int k0 = 0; k0 < K; k0 += 32) {
        __syncthreads();
        #pragma unroll
        for (int cc = 0; cc < 2; ++cc) {
            int c = t + cc * 256;
            int row = c >> 2, ko = (c & 3) << 3;
            half8 av = *(const half8*)&A[(size_t)(m0 + row) * K + k0 + ko];
            *(half8*)&As[row * 40 + ko] = av;
            half8 bv = *(const half8*)&Bp[(size_t)(n0 + row) * K + k0 + ko];
            *(half8*)&Bs[row * 40 + ko] = bv;
        }
        __syncthreads();

        int lr = lane & 15, lk = (lane >> 4) << 3;
        half8 af[4], bf[4];
        #pragma unroll
        for (int i = 0; i < 4; ++i)
            af[i] = *(const half8*)&As[(wr * 64 + i * 16 + lr) * 40 + lk];
        #pragma unroll
        for (int j = 0; j < 4; ++j)
            bf[j] = *(const half8*)&Bs[(wc * 64 + j * 16 + lr) * 40 + lk];
        #pragma unroll
        for (int i = 0; i < 4; ++i)
            #pragma unroll
            for (int j = 0; j < 4; ++j)
                acc[i][j] = __builtin_amdgcn_mfma_f32_16x16x32_f16(af[i], bf[j], acc[i][j], 0, 0, 0);
    }

    // epilogue: D mapping col=lane&15, row=(lane>>4)*4+q
    int lr = lane & 15, lq = (lane >> 4) * 4;
    #pragma unroll
    for (int j = 0; j < 4; ++j) {
        int col = n0 + wc * 64 + j * 16 + lr;
        if (col >= HPAD) continue;
        float bv = (col < 300) ? bias[col] : 0.f;
        #pragma unroll
        for (int i = 0; i < 4; ++i) {
            int rbase = m0 + wr * 64 + i * 16 + lq;
            #pragma unroll
            for (int q = 0; q < 4; ++q) {
                float v = acc[i][j][q] + bv;
                if (RELU) v = v > 0.f ? v : 0.f;
                if (col >= 300) v = 0.f;
                out[(size_t)(rbase + q) * HPAD + col] = (_Float16)v;
            }
        }
    }
}

// ---------------- CSR build ----------------
__global__ __launch_bounds__(256) void hist_kernel(const int* __restrict__ dst,
                                                   int* __restrict__ counts) {
    int e = blockIdx.x * 256 + threadIdx.x;
    if (e < N_EDGES) atomicAdd(&counts[dst[e]], 1);
}

// exclusive scan of 256 elements per block; emits block sums
__global__ __launch_bounds__(256) void scan_block(const int* __restrict__ in,
                                                  int* __restrict__ partial,
                                                  int* __restrict__ bsum, int nb) {
    __shared__ int s[256];
    int b = blockIdx.x, t = threadIdx.x;
    int v = (b < nb) ? in[b * 256 + t] : 0;
    s[t] = v;
    __syncthreads();
    for (int o = 1; o < 256; o <<= 1) {
        int x = (t >= o) ? s[t - o] : 0;
        __syncthreads();
        s[t] += x;
        __syncthreads();
    }
    partial[b * 256 + t] = s[t] - v;      // exclusive
    if (t == 255 && bsum) bsum[b] = s[255];
}

__global__ __launch_bounds__(256) void add_offsets(const int* __restrict__ partial,
                                                   const int* __restrict__ boff,
                                                   int* __restrict__ rowptr) {
    int i = blockIdx.x * 256 + threadIdx.x;
    if (i < N_NODES) rowptr[i] = partial[i] + boff[i >> 8];
    if (i == 0) rowptr[N_NODES] = N_EDGES;
}

__global__ __launch_bounds__(256) void scatter_csr(const int* __restrict__ src,
                                                   const int* __restrict__ dst,
                                                   const int* __restrict__ rowptr,
                                                   int* __restrict__ cnt,
                                                   int2* __restrict__ se) {
    int e = blockIdx.x * 256 + threadIdx.x;
    if (e >= N_EDGES) return;
    int d = dst[e];
    int pos = atomicAdd(&cnt[d], 1);
    se[rowptr[d] + pos] = make_int2(src[e], e);
}

// ---------------- gather: z[d] = h[d] + sum_{s in row(d)} relu(h[src_s] + ehcsr[s])
// ehcsr is in CSR order -> sequential streaming reads. 320 thr/block =
// 4 node-slots x 80 col-chunks (chunks 75..79 write pad zeros). Batch-4 edges.
__global__ __launch_bounds__(320) void gather_z(
        const _Float16* __restrict__ h, const _Float16* __restrict__ ehcsr,
        const int2* __restrict__ se, const int* __restrict__ rowptr,
        _Float16* __restrict__ z, int nblocks) {
    int t = threadIdx.x;
    int c = t % 80, ns = t / 80;
    bool active = c < 75;
    for (int node = blockIdx.x * 4 + ns; node < N_NODES; node += nblocks * 4) {
        int r0 = rowptr[node], r1 = rowptr[node + 1];
        half4 acc = {(_Float16)0, (_Float16)0, (_Float16)0, (_Float16)0};
        half4 hn = acc;
        if (active) {
            hn = *(const half4*)&h[(size_t)node * HPAD + c * 4];
            for (int s = r0; s < r1; s += 4) {
                int nb = r1 - s;
                int idx[4];
                idx[0] = s;
                idx[1] = s + (1 < nb ? 1 : 0);
                idx[2] = s + (2 < nb ? 2 : 0);
                idx[3] = s + (3 < nb ? 3 : 0);
                half4 hv[4], ev[4];
                #pragma unroll
                for (int u = 0; u < 4; ++u) {
                    int sp = se[idx[u]].x;
                    hv[u] = *(const half4*)&h[(size_t)sp * HPAD + c * 4];
                    ev[u] = *(const half4*)&ehcsr[(size_t)idx[u] * HPAD + c * 4];
                }
                #pragma unroll
                for (int u = 0; u < 4; ++u) {
                    half4 m = hv[u] + ev[u];
                    #pragma unroll
                    for (int j = 0; j < 4; ++j)
                        m[j] = m[j] > (_Float16)0 ? m[j] : (_Float16)0;
                    if (u < nb) acc += m;
                }
            }
        }
        half4 o = hn + acc;          // inactive lanes write 0 (pad cols 300..319)
        *(half4*)&z[(size_t)node * HPAD + c * 4] = o;
    }
}

// ---------------- per-molecule sum pool (32 consecutive rows)
__global__ __launch_bounds__(128) void pool_kernel(const _Float16* __restrict__ h,
                                                   float* __restrict__ out, int add) {
    int b = blockIdx.x, t = threadIdx.x;
    if (t >= 75) return;
    float a0 = 0, a1 = 0, a2 = 0, a3 = 0;
    for (int r = 0; r < 32; ++r) {
        half4 v = *(const half4*)&h[(size_t)(b * 32 + r) * HPAD + t * 4];
        a0 += (float)v[0]; a1 += (float)v[1]; a2 += (float)v[2]; a3 += (float)v[3];
    }
    f32x4 o = {a0, a1, a2, a3};
    if (add) o += *(f32x4*)&out[b * 300 + t * 4];
    *(f32x4*)&out[b * 300 + t * 4] = o;
}

__global__ __launch_bounds__(256) void diff_kernel(float* __restrict__ reaction,
                                                   const float* __restrict__ reactants,
                                                   const float* __restrict__ products, int n) {
    int i = blockIdx.x * 256 + threadIdx.x;
    if (i < n) reaction[i] = reactants[i] - products[i];
}

extern "C" void kernel_launch(void* const* d_in, const int* in_sizes, int n_in,
                              void* d_out, int out_size, void* d_ws, size_t ws_size,
                              hipStream_t stream) {
    const float* x[3]   = {(const float*)d_in[0], (const float*)d_in[5],  (const float*)d_in[10]};
    const float* ein[3] = {(const float*)d_in[1], (const float*)d_in[6],  (const float*)d_in[11]};
    const int*   src[3] = {(const int*)d_in[2],   (const int*)d_in[7],    (const int*)d_in[12]};
    const int*   dst[3] = {(const int*)d_in[3],   (const int*)d_in[8],    (const int*)d_in[13]};
    const float* Wn = (const float*)d_in[15];
    const float* bn = (const float*)d_in[16];
    const float* We = (const float*)d_in[17];
    const float* be = (const float*)d_in[18];
    const float* W1 = (const float*)d_in[19];
    const float* b1 = (const float*)d_in[20];
    const float* W2 = (const float*)d_in[21];
    const float* b2 = (const float*)d_in[22];

    char* ws = (char*)d_ws;
    size_t off = 0;
    auto alloc = [&](size_t bytes) {
        char* p = ws + off; off += (bytes + 1023) & ~(size_t)1023; return p;
    };
    _Float16* h     = (_Float16*)alloc((size_t)N_NODES * HPAD * 2);   // 40 MiB
    _Float16* zbuf  = (_Float16*)alloc((size_t)N_NODES * HPAD * 2);   // 40 MiB
    _Float16* tbuf  = (_Float16*)alloc((size_t)N_NODES * HPAD * 2);   // 40 MiB
    _Float16* ehcsr = (_Float16*)alloc((size_t)N_EDGES * HPAD * 2);   // 80 MiB
    int*      counts= (int*)alloc((size_t)N_NODES * 4);
    int*      part  = (int*)alloc((size_t)N_NODES * 4);
    int*      bsum  = (int*)alloc(256 * 4);
    int*      bpart = (int*)alloc(256 * 4);
    int*      bzero = (int*)alloc(4);
    int*      rowptr= (int*)alloc((size_t)(N_NODES + 1) * 4);
    int*      cnt   = (int*)alloc((size_t)N_NODES * 4);
    int2*     se    = (int2*)alloc((size_t)N_EDGES * 8);
    _Float16* Wt1   = (_Float16*)alloc((size_t)3 * 384 * HPAD * 2);
    _Float16* Wt2   = (_Float16*)alloc((size_t)3 * 384 * HPAD * 2);
    _Float16* Wnt   = (_Float16*)alloc((size_t)384 * 64 * 2);
    _Float16* Wet   = (_Float16*)alloc((size_t)384 * 32 * 2);
    // overlays (both dead before their hosts are written):
    _Float16* xh    = (_Float16*)zbuf;   // consumed by node-proj GEMM before gather writes zbuf
    _Float16* ecsr  = (_Float16*)tbuf;   // consumed by eh-GEMM before GEMM1 writes tbuf

    if (off > ws_size) return;   // graceful diagnostic failure if ws too small

    for (int l = 0; l < 3; ++l) {
        prepack_w<<<(384 * HPAD + 255) / 256, 256, 0, stream>>>(W1 + l * 90000, Wt1 + l * 384 * HPAD, HPAD, 300);
        prepack_w<<<(384 * HPAD + 255) / 256, 256, 0, stream>>>(W2 + l * 90000, Wt2 + l * 384 * HPAD, HPAD, 300);
    }
    prepack_w<<<(384 * 64 + 255) / 256, 256, 0, stream>>>(Wn, Wnt, 64, 64);
    prepack_w<<<(384 * 32 + 255) / 256, 256, 0, stream>>>(We, Wet, 32, 16);
    hipMemsetAsync(bzero, 0, 4, stream);

    float* outp      = (float*)d_out;
    float* reaction  = outp;
    float* reactants = outp + (size_t)BB * HDIM;
    float* products  = outp + (size_t)2 * BB * HDIM;

    const int EG = (N_EDGES + 255) / 256;
    for (int g = 0; g < 3; ++g) {
        // node projection: h = relu(x @ Wn + bn)
        cvt_x<<<(N_NODES * 64 + 255) / 256, 256, 0, stream>>>(x[g], xh, N_NODES * 64);
        gemm_f16<true><<<512 * 3, 256, 0, stream>>>(xh, Wnt, bn, h, N_NODES, 64);

        // CSR build (incoming edges per node)
        hipMemsetAsync(counts, 0, (size_t)N_NODES * 4, stream);
        hist_kernel<<<EG, 256, 0, stream>>>(dst[g], counts);
        scan_block<<<256, 256, 0, stream>>>(counts, part, bsum, 256);
        scan_block<<<1, 256, 0, stream>>>(bsum, bpart, bzero, 1);
        add_offsets<<<256, 256, 0, stream>>>(part, bpart, rowptr);
        hipMemsetAsync(cnt, 0, (size_t)N_NODES * 4, stream);
        scatter_csr<<<EG, 256, 0, stream>>>(src[g], dst[g], rowptr, cnt, se);

        // edge projection once per graph, in CSR order: ehcsr = ecsr @ We + be
        cvt_e_csr<<<(N_EDGES * 32 + 255) / 256, 256, 0, stream>>>(ein[g], se, ecsr);
        gemm_f16<false><<<1024 * 3, 256, 0, stream>>>(ecsr, Wet, be, ehcsr, N_EDGES, 32);

        for (int l = 0; l < 3; ++l) {
            gather_z<<<4096, 320, 0, stream>>>(h, ehcsr, se, rowptr, zbuf, 4096);
            // t = relu(z @ W1[l] + b1[l])
            gemm_f16<true><<<512 * 3, 256, 0, stream>>>(zbuf, Wt1 + l * 384 * HPAD, b1 + l * 300, tbuf, N_NODES, HPAD);
            // h = t @ W2[l] + b2[l]  (+relu if l<2)
            if (l < 2)
                gemm_f16<true ><<<512 * 3, 256, 0, stream>>>(tbuf, Wt2 + l * 384 * HPAD, b2 + l * 300, h, N_NODES, HPAD);
            else
                gemm_f16<false><<<512 * 3, 256, 0, stream>>>(tbuf, Wt2 + l * 384 * HPAD, b2 + l * 300, h, N_NODES, HPAD);
        }
        if (g == 0)      pool_kernel<<<BB, 128, 0, stream>>>(h, reactants, 0);
        else if (g == 1) pool_kernel<<<BB, 128, 0, stream>>>(h, reactants, 1);
        else             pool_kernel<<<BB, 128, 0, stream>>>(h, products, 0);
    }
    diff_kernel<<<((BB * HDIM) + 255) / 256, 256, 0, stream>>>(reaction, reactants, products, BB * HDIM);
}

// Round 6
// 1102.993 us; speedup vs baseline: 5.9853x; 1.2025x over previous
//
#include <hip/hip_runtime.h>

typedef _Float16 half8 __attribute__((ext_vector_type(8)));
typedef _Float16 half4 __attribute__((ext_vector_type(4)));
typedef float    f32x4 __attribute__((ext_vector_type(4)));

#define N_NODES 65536
#define N_EDGES 131072
#define BB      2048
#define HDIM    300
#define HPAD    320   // K padded to multiple of 32

// ---------------- prepack: dst[384][Kpad] = W[k][n]  (B^T panel, zero-padded)
__global__ __launch_bounds__(256) void prepack_w(const float* __restrict__ src,
                                                 _Float16* __restrict__ dst,
                                                 int Kpad, int Kreal) {
    int idx = blockIdx.x * 256 + threadIdx.x;
    int n = idx / Kpad, k = idx - n * Kpad;
    if (n >= 384) return;
    float v = (n < 300 && k < Kreal) ? src[k * 300 + n] : 0.f;
    dst[idx] = (_Float16)v;
}

__global__ __launch_bounds__(256) void cvt_x(const float* __restrict__ x,
                                             _Float16* __restrict__ xh, int n) {
    int i = blockIdx.x * 256 + threadIdx.x;
    if (i < n) xh[i] = (_Float16)x[i];
}

// edge feats -> f16, permuted into CSR order, zero-padded to 32 cols
__global__ __launch_bounds__(256) void cvt_e_csr(const float* __restrict__ ein,
                                                 const int2* __restrict__ se,
                                                 _Float16* __restrict__ ecsr) {
    int i = blockIdx.x * 256 + threadIdx.x;
    if (i >= N_EDGES * 32) return;
    int k = i & 31, s = i >> 5;
    int e = se[s].y;
    ecsr[i] = (_Float16)(k < 16 ? ein[(size_t)e * 16 + k] : 0.f);
}

__device__ __forceinline__ void gload16(const _Float16* g, _Float16* l) {
    __builtin_amdgcn_global_load_lds(
        (const __attribute__((address_space(1))) void*)g,
        (__attribute__((address_space(3))) void*)l, 16, 0, 0);
}

// ---------------- MFMA GEMM: out[M][320] = op( A[M][K] @ Bp^T ) + bias
// Bp is [384][K] f16. 128x128 tile, 4 waves, 64x64/wave.
// global_load_lds staging, 2-deep double buffer, counted vmcnt (T3/T4-min),
// XOR-swizzled LDS (pre-swizzled source + swizzled read), XCD-grouped blocks,
// LDS-transposed coalesced epilogue. Pad cols 300..319 written as zeros.
template <bool RELU>
__global__ __launch_bounds__(256) void gemm_f16(
        const _Float16* __restrict__ A,
        const _Float16* __restrict__ Bp, const float* __restrict__ bias,
        _Float16* __restrict__ out, int M, int K) {
    __shared__ _Float16 lds[2][2][128 * 32];   // [buf][A/B][row*32+k] : 32 KB

    // XCD grouping: the 3 nt-siblings of one mt land on the same XCD (bid%8)
    int bid = blockIdx.x;
    int xcd = bid & 7, grp = bid >> 3;
    int mt = xcd + 8 * (grp / 3);
    int nt = grp % 3;
    int m0 = mt * 128, n0 = nt * 128;
    int t = threadIdx.x;
    int lane = t & 63, w = t >> 6;
    int wr = w >> 1, wc = w & 1;

    // staging geometry: wave w stages 2 chunks of 16 rows each (1 KB per inst)
    // LDS slot (row, lane&3) <- global chunk (lane&3) ^ ((row>>1)&3)
    int srow[2], sko[2];
    #pragma unroll
    for (int q = 0; q < 2; ++q) {
        int row = (w * 2 + q) * 16 + (lane >> 2);
        int ch = (lane & 3) ^ ((row >> 1) & 3);
        srow[q] = row; sko[q] = ch * 8;
    }

    f32x4 acc[4][4] = {};
    int NK = K >> 5;

    auto stage = [&](int buf, int k0) {
        #pragma unroll
        for (int q = 0; q < 2; ++q) {
            gload16(&A[(size_t)(m0 + srow[q]) * K + k0 + sko[q]], &lds[buf][0][(w * 2 + q) * 512]);
            gload16(&Bp[(size_t)(n0 + srow[q]) * K + k0 + sko[q]], &lds[buf][1][(w * 2 + q) * 512]);
        }
    };

    stage(0, 0);
    for (int kt = 0; kt < NK; ++kt) {
        int cur = kt & 1;
        if (kt + 1 < NK) {
            stage(cur ^ 1, (kt + 1) << 5);
            asm volatile("s_waitcnt vmcnt(4)" ::: "memory");   // prev stage done, prefetch in flight
        } else {
            asm volatile("s_waitcnt vmcnt(0)" ::: "memory");
        }
        __builtin_amdgcn_s_barrier();
        __builtin_amdgcn_sched_barrier(0);

        int lr = lane & 15, hi = lane >> 4;
        half8 af[4], bf[4];
        #pragma unroll
        for (int i = 0; i < 4; ++i) {
            int row = wr * 64 + i * 16 + lr;
            int lk = (hi ^ ((row >> 1) & 3)) * 8;
            af[i] = *(const half8*)&lds[cur][0][row * 32 + lk];
        }
        #pragma unroll
        for (int j = 0; j < 4; ++j) {
            int row = wc * 64 + j * 16 + lr;
            int lk = (hi ^ ((row >> 1) & 3)) * 8;
            bf[j] = *(const half8*)&lds[cur][1][row * 32 + lk];
        }
        #pragma unroll
        for (int i = 0; i < 4; ++i)
            #pragma unroll
            for (int j = 0; j < 4; ++j)
                acc[i][j] = __builtin_amdgcn_mfma_f32_16x16x32_f16(af[i], bf[j], acc[i][j], 0, 0, 0);

        __builtin_amdgcn_sched_barrier(0);
        __builtin_amdgcn_s_barrier();
    }
    __builtin_amdgcn_sched_barrier(0);

    // epilogue: acc -> LDS (f16, 128x128) -> coalesced 256B stores
    _Float16* ct = &lds[0][0][0];
    {
        int lr = lane & 15, lq = (lane >> 4) * 4;
        #pragma unroll
        for (int j = 0; j < 4; ++j) {
            int col = wc * 64 + j * 16 + lr;
            int gcol = n0 + col;
            float bv = (gcol < 300) ? bias[gcol] : 0.f;
            #pragma unroll
            for (int i = 0; i < 4; ++i) {
                int rbase = wr * 64 + i * 16 + lq;
                #pragma unroll
                for (int q = 0; q < 4; ++q) {
                    float v = acc[i][j][q] + bv;
                    if (RELU) v = v > 0.f ? v : 0.f;
                    if (gcol >= 300) v = 0.f;
                    ct[(rbase + q) * 128 + col] = (_Float16)v;
                }
            }
        }
    }
    __syncthreads();
    #pragma unroll
    for (int r = 0; r < 8; ++r) {
        int row = r * 16 + (t >> 4);
        int c8 = (t & 15) * 8;
        if (n0 + c8 < HPAD) {
            half8 v = *(const half8*)&ct[row * 128 + c8];
            *(half8*)&out[(size_t)(m0 + row) * HPAD + n0 + c8] = v;
        }
    }
}

// ---------------- CSR build ----------------
__global__ __launch_bounds__(256) void hist_kernel(const int* __restrict__ dst,
                                                   int* __restrict__ counts) {
    int e = blockIdx.x * 256 + threadIdx.x;
    if (e < N_EDGES) atomicAdd(&counts[dst[e]], 1);
}

__global__ __launch_bounds__(256) void scan_block(const int* __restrict__ in,
                                                  int* __restrict__ partial,
                                                  int* __restrict__ bsum, int nb) {
    __shared__ int s[256];
    int b = blockIdx.x, t = threadIdx.x;
    int v = (b < nb) ? in[b * 256 + t] : 0;
    s[t] = v;
    __syncthreads();
    for (int o = 1; o < 256; o <<= 1) {
        int x = (t >= o) ? s[t - o] : 0;
        __syncthreads();
        s[t] += x;
        __syncthreads();
    }
    partial[b * 256 + t] = s[t] - v;      // exclusive
    if (t == 255 && bsum) bsum[b] = s[255];
}

__global__ __launch_bounds__(256) void add_offsets(const int* __restrict__ partial,
                                                   const int* __restrict__ boff,
                                                   int* __restrict__ rowptr) {
    int i = blockIdx.x * 256 + threadIdx.x;
    if (i < N_NODES) rowptr[i] = partial[i] + boff[i >> 8];
    if (i == 0) rowptr[N_NODES] = N_EDGES;
}

__global__ __launch_bounds__(256) void scatter_csr(const int* __restrict__ src,
                                                   const int* __restrict__ dst,
                                                   const int* __restrict__ rowptr,
                                                   int* __restrict__ cnt,
                                                   int2* __restrict__ se) {
    int e = blockIdx.x * 256 + threadIdx.x;
    if (e >= N_EDGES) return;
    int d = dst[e];
    int pos = atomicAdd(&cnt[d], 1);
    se[rowptr[d] + pos] = make_int2(src[e], e);
}

// ---------------- gather: z[d] = h[d] + sum_{s in row(d)} relu(h[src_s] + ehcsr[s])
__global__ __launch_bounds__(320) void gather_z(
        const _Float16* __restrict__ h, const _Float16* __restrict__ ehcsr,
        const int2* __restrict__ se, const int* __restrict__ rowptr,
        _Float16* __restrict__ z, int nblocks) {
    int t = threadIdx.x;
    int c = t % 80, ns = t / 80;
    bool active = c < 75;
    for (int node = blockIdx.x * 4 + ns; node < N_NODES; node += nblocks * 4) {
        int r0 = rowptr[node], r1 = rowptr[node + 1];
        half4 acc = {(_Float16)0, (_Float16)0, (_Float16)0, (_Float16)0};
        half4 hn = acc;
        if (active) {
            hn = *(const half4*)&h[(size_t)node * HPAD + c * 4];
            for (int s = r0; s < r1; s += 4) {
                int nb = r1 - s;
                int idx[4];
                idx[0] = s;
                idx[1] = s + (1 < nb ? 1 : 0);
                idx[2] = s + (2 < nb ? 2 : 0);
                idx[3] = s + (3 < nb ? 3 : 0);
                half4 hv[4], ev[4];
                #pragma unroll
                for (int u = 0; u < 4; ++u) {
                    int sp = se[idx[u]].x;
                    hv[u] = *(const half4*)&h[(size_t)sp * HPAD + c * 4];
                    ev[u] = *(const half4*)&ehcsr[(size_t)idx[u] * HPAD + c * 4];
                }
                #pragma unroll
                for (int u = 0; u < 4; ++u) {
                    half4 m = hv[u] + ev[u];
                    #pragma unroll
                    for (int j = 0; j < 4; ++j)
                        m[j] = m[j] > (_Float16)0 ? m[j] : (_Float16)0;
                    if (u < nb) acc += m;
                }
            }
        }
        half4 o = hn + acc;          // inactive lanes write 0 (pad cols 300..319)
        *(half4*)&z[(size_t)node * HPAD + c * 4] = o;
    }
}

// ---------------- per-molecule sum pool (32 consecutive rows)
__global__ __launch_bounds__(128) void pool_kernel(const _Float16* __restrict__ h,
                                                   float* __restrict__ out, int add) {
    int b = blockIdx.x, t = threadIdx.x;
    if (t >= 75) return;
    float a0 = 0, a1 = 0, a2 = 0, a3 = 0;
    for (int r = 0; r < 32; ++r) {
        half4 v = *(const half4*)&h[(size_t)(b * 32 + r) * HPAD + t * 4];
        a0 += (float)v[0]; a1 += (float)v[1]; a2 += (float)v[2]; a3 += (float)v[3];
    }
    f32x4 o = {a0, a1, a2, a3};
    if (add) o += *(f32x4*)&out[b * 300 + t * 4];
    *(f32x4*)&out[b * 300 + t * 4] = o;
}

__global__ __launch_bounds__(256) void diff_kernel(float* __restrict__ reaction,
                                                   const float* __restrict__ reactants,
                                                   const float* __restrict__ products, int n) {
    int i = blockIdx.x * 256 + threadIdx.x;
    if (i < n) reaction[i] = reactants[i] - products[i];
}

extern "C" void kernel_launch(void* const* d_in, const int* in_sizes, int n_in,
                              void* d_out, int out_size, void* d_ws, size_t ws_size,
                              hipStream_t stream) {
    const float* x[3]   = {(const float*)d_in[0], (const float*)d_in[5],  (const float*)d_in[10]};
    const float* ein[3] = {(const float*)d_in[1], (const float*)d_in[6],  (const float*)d_in[11]};
    const int*   src[3] = {(const int*)d_in[2],   (const int*)d_in[7],    (const int*)d_in[12]};
    const int*   dst[3] = {(const int*)d_in[3],   (const int*)d_in[8],    (const int*)d_in[13]};
    const float* Wn = (const float*)d_in[15];
    const float* bn = (const float*)d_in[16];
    const float* We = (const float*)d_in[17];
    const float* be = (const float*)d_in[18];
    const float* W1 = (const float*)d_in[19];
    const float* b1 = (const float*)d_in[20];
    const float* W2 = (const float*)d_in[21];
    const float* b2 = (const float*)d_in[22];

    char* ws = (char*)d_ws;
    size_t off = 0;
    auto alloc = [&](size_t bytes) {
        char* p = ws + off; off += (bytes + 1023) & ~(size_t)1023; return p;
    };
    _Float16* h     = (_Float16*)alloc((size_t)N_NODES * HPAD * 2);   // 40 MiB
    _Float16* zbuf  = (_Float16*)alloc((size_t)N_NODES * HPAD * 2);   // 40 MiB
    _Float16* tbuf  = (_Float16*)alloc((size_t)N_NODES * HPAD * 2);   // 40 MiB
    _Float16* ehcsr = (_Float16*)alloc((size_t)N_EDGES * HPAD * 2);   // 80 MiB
    int*      counts= (int*)alloc((size_t)N_NODES * 4);
    int*      part  = (int*)alloc((size_t)N_NODES * 4);
    int*      bsum  = (int*)alloc(256 * 4);
    int*      bpart = (int*)alloc(256 * 4);
    int*      bzero = (int*)alloc(4);
    int*      rowptr= (int*)alloc((size_t)(N_NODES + 1) * 4);
    int*      cnt   = (int*)alloc((size_t)N_NODES * 4);
    int2*     se    = (int2*)alloc((size_t)N_EDGES * 8);
    _Float16* Wt1   = (_Float16*)alloc((size_t)3 * 384 * HPAD * 2);
    _Float16* Wt2   = (_Float16*)alloc((size_t)3 * 384 * HPAD * 2);
    _Float16* Wnt   = (_Float16*)alloc((size_t)384 * 64 * 2);
    _Float16* Wet   = (_Float16*)alloc((size_t)384 * 32 * 2);
    // overlays (both dead before their hosts are written):
    _Float16* xh    = (_Float16*)zbuf;   // consumed by node-proj GEMM before gather writes zbuf
    _Float16* ecsr  = (_Float16*)tbuf;   // consumed by eh-GEMM before GEMM1 writes tbuf

    if (off > ws_size) return;   // graceful diagnostic failure if ws too small

    for (int l = 0; l < 3; ++l) {
        prepack_w<<<(384 * HPAD + 255) / 256, 256, 0, stream>>>(W1 + l * 90000, Wt1 + l * 384 * HPAD, HPAD, 300);
        prepack_w<<<(384 * HPAD + 255) / 256, 256, 0, stream>>>(W2 + l * 90000, Wt2 + l * 384 * HPAD, HPAD, 300);
    }
    prepack_w<<<(384 * 64 + 255) / 256, 256, 0, stream>>>(Wn, Wnt, 64, 64);
    prepack_w<<<(384 * 32 + 255) / 256, 256, 0, stream>>>(We, Wet, 32, 16);
    hipMemsetAsync(bzero, 0, 4, stream);

    float* outp      = (float*)d_out;
    float* reaction  = outp;
    float* reactants = outp + (size_t)BB * HDIM;
    float* products  = outp + (size_t)2 * BB * HDIM;

    const int EG = (N_EDGES + 255) / 256;
    for (int g = 0; g < 3; ++g) {
        // node projection: h = relu(x @ Wn + bn)
        cvt_x<<<(N_NODES * 64 + 255) / 256, 256, 0, stream>>>(x[g], xh, N_NODES * 64);
        gemm_f16<true><<<512 * 3, 256, 0, stream>>>(xh, Wnt, bn, h, N_NODES, 64);

        // CSR build (incoming edges per node)
        hipMemsetAsync(counts, 0, (size_t)N_NODES * 4, stream);
        hist_kernel<<<EG, 256, 0, stream>>>(dst[g], counts);
        scan_block<<<256, 256, 0, stream>>>(counts, part, bsum, 256);
        scan_block<<<1, 256, 0, stream>>>(bsum, bpart, bzero, 1);
        add_offsets<<<256, 256, 0, stream>>>(part, bpart, rowptr);
        hipMemsetAsync(cnt, 0, (size_t)N_NODES * 4, stream);
        scatter_csr<<<EG, 256, 0, stream>>>(src[g], dst[g], rowptr, cnt, se);

        // edge projection once per graph, in CSR order: ehcsr = ecsr @ We + be
        cvt_e_csr<<<(N_EDGES * 32 + 255) / 256, 256, 0, stream>>>(ein[g], se, ecsr);
        gemm_f16<false><<<1024 * 3, 256, 0, stream>>>(ecsr, Wet, be, ehcsr, N_EDGES, 32);

        for (int l = 0; l < 3; ++l) {
            gather_z<<<4096, 320, 0, stream>>>(h, ehcsr, se, rowptr, zbuf, 4096);
            // t = relu(z @ W1[l] + b1[l])
            gemm_f16<true><<<512 * 3, 256, 0, stream>>>(zbuf, Wt1 + l * 384 * HPAD, b1 + l * 300, tbuf, N_NODES, HPAD);
            // h = t @ W2[l] + b2[l]  (+relu if l<2)
            if (l < 2)
                gemm_f16<true ><<<512 * 3, 256, 0, stream>>>(tbuf, Wt2 + l * 384 * HPAD, b2 + l * 300, h, N_NODES, HPAD);
            else
                gemm_f16<false><<<512 * 3, 256, 0, stream>>>(tbuf, Wt2 + l * 384 * HPAD, b2 + l * 300, h, N_NODES, HPAD);
        }
        if (g == 0)      pool_kernel<<<BB, 128, 0, stream>>>(h, reactants, 0);
        else if (g == 1) pool_kernel<<<BB, 128, 0, stream>>>(h, reactants, 1);
        else             pool_kernel<<<BB, 128, 0, stream>>>(h, products, 0);
    }
    diff_kernel<<<((BB * HDIM) + 255) / 256, 256, 0, stream>>>(reaction, reactants, products, BB * HDIM);
}